// Round 15
// baseline (744.888 us; speedup 1.0000x reference)
//
#include <hip/hip_runtime.h>
#include <hip/hip_bf16.h>
#include <stdint.h>

#define N_NODES 262144
#define E_EDGES 4194304
#define SRC_OFF 524288
#define DST_OFF (524288 + 4194310)
#define W_OFF   (524288 + 2 * 4194310)

using bf16 = __hip_bfloat16;
typedef float f4v __attribute__((ext_vector_type(4)));
typedef float f2v __attribute__((ext_vector_type(2)));

__device__ __forceinline__ float b2f(unsigned int u) {
    union { unsigned int i; float f; } v; v.i = u << 16; return v.f;
}

// raw packed 2xbf16 atomic add (fire-and-forget; hs pre-scaled by dinv[s])
__device__ __forceinline__ void pk_atomic_add_raw(bf16* addr, uint32_t data) {
    asm volatile("global_atomic_pk_add_bf16 %0, %1, off" :: "v"(addr), "v"(data) : "memory");
}

// inline symmetric-norm factor: dinv(i) = rsqrt(deg[i] + 1 [+1 if pad endpoint])
__device__ __forceinline__ float dinv_of(const float* __restrict__ deg, int i, int n, int pads) {
    float extra = (pads && (i == 0 || i == n - 1)) ? 1.0f : 0.0f;
    return rsqrtf(deg[i] + 1.0f + extra);
}

// ---------------------------------------------------------------------------
// 1) hist: thread-per-8-edges, LOOP-FREE, NO ballots/counters/compaction.
// Edge outputs (NT stores) + deg1 scattered atomics + pad output slots.
// ---------------------------------------------------------------------------
__global__ void __launch_bounds__(256) hist_kernel(const int* __restrict__ ei,
        float* __restrict__ out, float* __restrict__ deg1) {
    int t = blockIdx.x * 256 + threadIdx.x;          // t < E/8 = 524288
    int4 s0 = ((const int4*)ei)[2 * t];
    int4 s1 = ((const int4*)ei)[2 * t + 1];
    int4 d0 = ((const int4*)(ei + E_EDGES))[2 * t];
    int4 d1 = ((const int4*)(ei + E_EDGES))[2 * t + 1];

    f4v v;
    v = (f4v){(float)s0.x, (float)s0.y, (float)s0.z, (float)s0.w};
    __builtin_nontemporal_store(v, (f4v*)(out + SRC_OFF) + 2 * t);
    v = (f4v){(float)s1.x, (float)s1.y, (float)s1.z, (float)s1.w};
    __builtin_nontemporal_store(v, (f4v*)(out + SRC_OFF) + 2 * t + 1);
    f2v w2;
    w2 = (f2v){(float)d0.x, (float)d0.y}; __builtin_nontemporal_store(w2, (f2v*)(out + DST_OFF) + 4 * t);
    w2 = (f2v){(float)d0.z, (float)d0.w}; __builtin_nontemporal_store(w2, (f2v*)(out + DST_OFF) + 4 * t + 1);
    w2 = (f2v){(float)d1.x, (float)d1.y}; __builtin_nontemporal_store(w2, (f2v*)(out + DST_OFF) + 4 * t + 2);
    w2 = (f2v){(float)d1.z, (float)d1.w}; __builtin_nontemporal_store(w2, (f2v*)(out + DST_OFF) + 4 * t + 3);
    v = (f4v){(s0.x < 32768 && d0.x < 32768) ? 1.0f : 0.0f,
              (s0.y < 32768 && d0.y < 32768) ? 1.0f : 0.0f,
              (s0.z < 32768 && d0.z < 32768) ? 1.0f : 0.0f,
              (s0.w < 32768 && d0.w < 32768) ? 1.0f : 0.0f};
    __builtin_nontemporal_store(v, (f4v*)(out + W_OFF) + 2 * t);
    v = (f4v){(s1.x < 32768 && d1.x < 32768) ? 1.0f : 0.0f,
              (s1.y < 32768 && d1.y < 32768) ? 1.0f : 0.0f,
              (s1.z < 32768 && d1.z < 32768) ? 1.0f : 0.0f,
              (s1.w < 32768 && d1.w < 32768) ? 1.0f : 0.0f};
    __builtin_nontemporal_store(v, (f4v*)(out + W_OFF) + 2 * t + 1);

    atomicAdd(&deg1[d0.x], 1.0f); atomicAdd(&deg1[d0.y], 1.0f);
    atomicAdd(&deg1[d0.z], 1.0f); atomicAdd(&deg1[d0.w], 1.0f);
    atomicAdd(&deg1[d1.x], 1.0f); atomicAdd(&deg1[d1.y], 1.0f);
    atomicAdd(&deg1[d1.z], 1.0f); atomicAdd(&deg1[d1.w], 1.0f);

    if (blockIdx.x == 0 && threadIdx.x < 6) {   // pad output slots E..E+5
        int k = threadIdx.x;
        int stage = k >> 1, m = 131072 >> stage;
        int s, d;
        if ((k & 1) == 0) { s = m - 1; d = 0; } else { s = 0; d = m - 1; }
        int e = E_EDGES + k;
        out[SRC_OFF + e] = (float)s;
        out[DST_OFF + e] = (float)d;
        out[W_OFF + e]   = (stage == 2) ? 1.0f : 0.0f;
    }
}

// ---------------------------------------------------------------------------
// 2a) xform (stage 1): hs = dinv1*(x@W) bf16; agg init = hs (self-loop term).
// ---------------------------------------------------------------------------
__global__ void __launch_bounds__(256) xform1_kernel(const float* __restrict__ xin,
        const float* __restrict__ W, const float* __restrict__ deg1,
        bf16* __restrict__ hs, bf16* __restrict__ agg) {
    constexpr int FIN = 32, FOUT = 32, NPB = 8;
    __shared__ float sW[FIN * FOUT];
    __shared__ float sx[NPB * FIN];
    int tid = threadIdx.x;
    for (int i = tid; i < FIN * FOUT; i += 256) sW[i] = W[i];
    int node0 = blockIdx.x * NPB;
    for (int i = tid; i < NPB * FIN; i += 256) sx[i] = xin[node0 * FIN + i];
    __syncthreads();
    int nl = tid / FOUT, j = tid % FOUT;
    int node = node0 + nl;
    float acc = 0.0f;
#pragma unroll
    for (int k = 0; k < FIN; ++k) acc += sx[nl * FIN + k] * sW[k * FOUT + j];
    bf16 v = __float2bfloat16(rsqrtf(deg1[node] + 1.0f) * acc);
    hs[node * FOUT + j]  = v;
    agg[node * FOUT + j] = v;
}

// ---------------------------------------------------------------------------
// 2b) xform_pool (stages 2/3): pool previous agg inline during staging, then
// hs = dinv*(x@W); agg init = hs. dinv recomputed inline from deg.
// ---------------------------------------------------------------------------
template <int FOUT>
__global__ void __launch_bounds__(256) xform_pool_kernel(const bf16* __restrict__ aggp,
        const float* __restrict__ degp, int prevN, int prevPads, const float* __restrict__ biasp,
        const float* __restrict__ W, const float* __restrict__ deg, int curN,
        bf16* __restrict__ hs, bf16* __restrict__ agg) {
    constexpr int FIN = 32;
    constexpr int NPB = 256 / FOUT;
    __shared__ float sW[FIN * FOUT];
    __shared__ float sx[NPB * FIN];
    const unsigned short* ap = (const unsigned short*)aggp;
    int tid = threadIdx.x;
    for (int i = tid; i < FIN * FOUT; i += 256) sW[i] = W[i];
    int node0 = blockIdx.x * NPB;
    for (int i = tid; i < NPB * FIN; i += 256) {
        int nl = i / FIN, k = i % FIN;
        int g0 = 2 * (node0 + nl);
        float bb = biasp[k];
        float v0 = dinv_of(degp, g0,     prevN, prevPads) * b2f(ap[(size_t)g0 * FIN + k])       + bb;
        float v1 = dinv_of(degp, g0 + 1, prevN, prevPads) * b2f(ap[(size_t)(g0 + 1) * FIN + k]) + bb;
        sx[i] = fmaxf(fmaxf(v0, v1), 0.0f);
    }
    __syncthreads();
    int nl = tid / FOUT, j = tid % FOUT;
    int node = node0 + nl;
    float acc = 0.0f;
#pragma unroll
    for (int k = 0; k < FIN; ++k) acc += sx[nl * FIN + k] * sW[k * FOUT + j];
    bf16 v = __float2bfloat16(dinv_of(deg, node, curN, 1) * acc);
    hs[node * FOUT + j]  = v;
    agg[node * FOUT + j] = v;
}

// ---------------------------------------------------------------------------
// 3) scatter1 (r11-proven 212 us shape) + FUSED deg2/deg3 atomics on the
// p==0 lane (+1.6M ops on a 67M-op atomic-bound kernel: ~+5 us). deg2/3 are
// ready exactly when xform_pool2 (next launch) needs them.
// ---------------------------------------------------------------------------
__global__ void __launch_bounds__(256) scatter1_kernel(const int* __restrict__ ei,
        const bf16* __restrict__ hs, bf16* __restrict__ agg,
        float* __restrict__ deg2, float* __restrict__ deg3) {
    unsigned idx = blockIdx.x * 256u + threadIdx.x;
    int e = (int)(idx >> 4), p = (int)(idx & 15u);
    int s = ei[e], d = ei[E_EDGES + e];
    if (p == 0 && s < 131072 && d < 131072) {
        atomicAdd(&deg2[d], 1.0f);
        if (s < 65536 && d < 65536) atomicAdd(&deg3[d], 1.0f);
    }
    uint32_t hw = *(const uint32_t*)((const unsigned short*)hs + (size_t)s * 32 + 2 * p);
    pk_atomic_add_raw(agg + (size_t)d * 32 + 2 * p, hw);
}

// ---------------------------------------------------------------------------
// 4) scatter2: masked full scan of ei (L3-hot), exec-mask early exit; 25%
// valid; 16 lanes/edge; +2 pad edges. Atomic work identical to compacted.
// ---------------------------------------------------------------------------
__global__ void __launch_bounds__(256) scatter2_kernel(const int* __restrict__ ei,
        const bf16* __restrict__ hs, bf16* __restrict__ agg) {
    unsigned idx = blockIdx.x * 256u + threadIdx.x;
    unsigned e = idx >> 4; int p = (int)(idx & 15u);
    int s, d;
    if (e < E_EDGES) {
        s = ei[e]; d = ei[E_EDGES + e];
        if (s >= 131072 || d >= 131072) return;
    }
    else if (e == E_EDGES)     { s = 131071; d = 0; }
    else if (e == E_EDGES + 1) { s = 0; d = 131071; }
    else return;
    uint32_t hw = *(const uint32_t*)((const unsigned short*)hs + (size_t)s * 32 + 2 * p);
    pk_atomic_add_raw(agg + (size_t)d * 32 + 2 * p, hw);
}

// ---------------------------------------------------------------------------
// 5) scatter3: masked full scan, 6.25% valid, 8 lanes/edge, FOUT = 16.
// ---------------------------------------------------------------------------
__global__ void __launch_bounds__(256) scatter3_kernel(const int* __restrict__ ei,
        const bf16* __restrict__ hs, bf16* __restrict__ agg) {
    unsigned idx = blockIdx.x * 256u + threadIdx.x;
    unsigned e = idx >> 3; int p = (int)(idx & 7u);
    int s, d;
    if (e < E_EDGES) {
        s = ei[e]; d = ei[E_EDGES + e];
        if (s >= 65536 || d >= 65536) return;
    }
    else if (e == E_EDGES)     { s = 65535; d = 0; }
    else if (e == E_EDGES + 1) { s = 0; d = 65535; }
    else return;
    uint32_t hw = *(const uint32_t*)((const unsigned short*)hs + (size_t)s * 16 + 2 * p);
    pk_atomic_add_raw(agg + (size_t)d * 16 + 2 * p, hw);
}

// ---------------------------------------------------------------------------
// 6) final pool: out(f32) = relu(max over pair of dinv3*agg3 + b3)
// ---------------------------------------------------------------------------
__global__ void __launch_bounds__(256) pool_out_kernel(const bf16* __restrict__ agg,
        const float* __restrict__ deg3, const float* __restrict__ bias,
        float* __restrict__ outp) {
    unsigned idx = blockIdx.x * 256u + threadIdx.x;   // < 32768*16
    int i = (int)(idx >> 4), f = (int)(idx & 15);
    int g0 = 2 * i;
    float bb = bias[f];
    float v0 = dinv_of(deg3, g0,     65536, 1) * __bfloat162float(agg[(size_t)g0 * 16 + f])       + bb;
    float v1 = dinv_of(deg3, g0 + 1, 65536, 1) * __bfloat162float(agg[(size_t)(g0 + 1) * 16 + f]) + bb;
    outp[idx] = fmaxf(fmaxf(v0, v1), 0.0f);
}

// ---------------------------------------------------------------------------
// Workspace (<57 MiB):
//  @0M  agg bf16 (16/8/2 MB per stage)   @16M hs bf16 (16/8/2 MB)
//  @55M deg1 (1M) @56M deg2 (.5M) @56.5M deg3 (.25M)
// ---------------------------------------------------------------------------
extern "C" void kernel_launch(void* const* d_in, const int* in_sizes, int n_in,
                              void* d_out, int out_size, void* d_ws, size_t ws_size,
                              hipStream_t stream) {
    const float* x  = (const float*)d_in[0];
    const int*   ei = (const int*)d_in[1];
    const float* W1 = (const float*)d_in[2];
    const float* b1 = (const float*)d_in[3];
    const float* W2 = (const float*)d_in[4];
    const float* b2 = (const float*)d_in[5];
    const float* W3 = (const float*)d_in[6];
    const float* b3 = (const float*)d_in[7];
    float* out = (float*)d_out;

    char* ws = (char*)d_ws;
    bf16*  agg  = (bf16*)ws;
    bf16*  hs   = (bf16*)(ws + (16u << 20));
    float* deg1 = (float*)(ws + (55u << 20));
    float* deg2 = (float*)(ws + (56u << 20));
    float* deg3 = (float*)(ws + (56u << 20) + (512u << 10));

    // zero deg1+deg2+deg3 (contiguous 1.75 MB)
    hipMemsetAsync(deg1, 0, (1u << 20) + (768u << 10), stream);

    // prep: outputs + deg1 only (no compaction machinery)
    hist_kernel<<<2048, 256, 0, stream>>>(ei, out, deg1);

    // stage 1: n=262144, 32->32 (all edges; deg2/3 ride the atomic-bound kernel)
    xform1_kernel<<<N_NODES / 8, 256, 0, stream>>>(x, W1, deg1, hs, agg);
    scatter1_kernel<<<E_EDGES * 16 / 256, 256, 0, stream>>>(ei, hs, agg, deg2, deg3);

    // stage 2: n=131072, 32->32 (pool fused into xform; masked full scan + pads)
    xform_pool_kernel<32><<<131072 / 8, 256, 0, stream>>>(agg, deg1, 262144, 0, b1,
                                                          W2, deg2, 131072, hs, agg);
    scatter2_kernel<<<(int)((((unsigned)E_EDGES + 2) * 16 + 255) / 256), 256, 0, stream>>>(
        ei, hs, agg);

    // stage 3: n=65536, 32->16 (pool fused; masked full scan + pads)
    xform_pool_kernel<16><<<65536 / 16, 256, 0, stream>>>(agg, deg2, 131072, 1, b2,
                                                          W3, deg3, 65536, hs, agg);
    scatter3_kernel<<<(int)((((unsigned)E_EDGES + 2) * 8 + 255) / 256), 256, 0, stream>>>(
        ei, hs, agg);

    // final pool -> f32 out
    pool_out_kernel<<<32768 * 16 / 256, 256, 0, stream>>>(agg, deg3, b3, out);
}

// Round 16
// 662.474 us; speedup vs baseline: 1.1244x; 1.1244x over previous
//
#include <hip/hip_runtime.h>
#include <hip/hip_bf16.h>
#include <stdint.h>

#define N_NODES 262144
#define E_EDGES 4194304
#define SRC_OFF 524288
#define DST_OFF (524288 + 4194310)
#define W_OFF   (524288 + 2 * 4194310)
#define CAP2    1064960            // el capacity (t3+t2 expected 1.0486M, +17 sigma)
#define CAP3    270336             // scatter3 edge cap (expected 262144, +16 sigma)

using bf16 = __hip_bfloat16;
typedef float f4v __attribute__((ext_vector_type(4)));
typedef float f2v __attribute__((ext_vector_type(2)));

__device__ __forceinline__ float b2f(unsigned int u) {
    union { unsigned int i; float f; } v; v.i = u << 16; return v.f;
}

// raw packed 2xbf16 atomic add (fire-and-forget; hs pre-scaled by dinv[s])
__device__ __forceinline__ void pk_atomic_add_raw(bf16* addr, uint32_t data) {
    asm volatile("global_atomic_pk_add_bf16 %0, %1, off" :: "v"(addr), "v"(data) : "memory");
}

// inline symmetric-norm factor: dinv(i) = rsqrt(deg[i] + 1 [+1 if pad endpoint])
__device__ __forceinline__ float dinv_of(const float* __restrict__ deg, int i, int n, int pads) {
    float extra = (pads && (i == 0 || i == n - 1)) ? 1.0f : 0.0f;
    return rsqrtf(deg[i] + 1.0f + extra);
}

// ---------------------------------------------------------------------------
// 1a) out_count: thread-per-8-edges, PURE streaming (NT stores) + per-wave
// tier counts (VALU-only shfl reduce). NO atomics — tests the sequencing
// hypothesis: prep mixing loads+atomics+stores ran at 1.5% VALU / 8% HBM.
// ---------------------------------------------------------------------------
__global__ void __launch_bounds__(256) out_count_kernel(const int* __restrict__ ei,
        float* __restrict__ out, uint32_t* __restrict__ wc) {
    int t = blockIdx.x * 256 + threadIdx.x;          // t < E/8 = 524288
    int4 s0 = ((const int4*)ei)[2 * t];
    int4 s1 = ((const int4*)ei)[2 * t + 1];
    int4 d0 = ((const int4*)(ei + E_EDGES))[2 * t];
    int4 d1 = ((const int4*)(ei + E_EDGES))[2 * t + 1];

    f4v v;
    v = (f4v){(float)s0.x, (float)s0.y, (float)s0.z, (float)s0.w};
    __builtin_nontemporal_store(v, (f4v*)(out + SRC_OFF) + 2 * t);
    v = (f4v){(float)s1.x, (float)s1.y, (float)s1.z, (float)s1.w};
    __builtin_nontemporal_store(v, (f4v*)(out + SRC_OFF) + 2 * t + 1);
    f2v w2;
    w2 = (f2v){(float)d0.x, (float)d0.y}; __builtin_nontemporal_store(w2, (f2v*)(out + DST_OFF) + 4 * t);
    w2 = (f2v){(float)d0.z, (float)d0.w}; __builtin_nontemporal_store(w2, (f2v*)(out + DST_OFF) + 4 * t + 1);
    w2 = (f2v){(float)d1.x, (float)d1.y}; __builtin_nontemporal_store(w2, (f2v*)(out + DST_OFF) + 4 * t + 2);
    w2 = (f2v){(float)d1.z, (float)d1.w}; __builtin_nontemporal_store(w2, (f2v*)(out + DST_OFF) + 4 * t + 3);
    v = (f4v){(s0.x < 32768 && d0.x < 32768) ? 1.0f : 0.0f,
              (s0.y < 32768 && d0.y < 32768) ? 1.0f : 0.0f,
              (s0.z < 32768 && d0.z < 32768) ? 1.0f : 0.0f,
              (s0.w < 32768 && d0.w < 32768) ? 1.0f : 0.0f};
    __builtin_nontemporal_store(v, (f4v*)(out + W_OFF) + 2 * t);
    v = (f4v){(s1.x < 32768 && d1.x < 32768) ? 1.0f : 0.0f,
              (s1.y < 32768 && d1.y < 32768) ? 1.0f : 0.0f,
              (s1.z < 32768 && d1.z < 32768) ? 1.0f : 0.0f,
              (s1.w < 32768 && d1.w < 32768) ? 1.0f : 0.0f};
    __builtin_nontemporal_store(v, (f4v*)(out + W_OFF) + 2 * t + 1);

    int ss[8] = {s0.x, s0.y, s0.z, s0.w, s1.x, s1.y, s1.z, s1.w};
    int dd[8] = {d0.x, d0.y, d0.z, d0.w, d1.x, d1.y, d1.z, d1.w};
    int c3 = 0, c2 = 0;
#pragma unroll
    for (int j = 0; j < 8; ++j) {
        bool b3  = (ss[j] < 65536) & (dd[j] < 65536);
        bool b23 = (ss[j] < 131072) & (dd[j] < 131072);
        c3 += b3; c2 += (b23 & !b3);
    }
    int pk = c2 | (c3 << 16);   // fields <= 512, no overflow
    pk += __shfl_xor(pk, 32); pk += __shfl_xor(pk, 16); pk += __shfl_xor(pk, 8);
    pk += __shfl_xor(pk, 4);  pk += __shfl_xor(pk, 2);  pk += __shfl_xor(pk, 1);
    if ((threadIdx.x & 63) == 0) wc[t >> 6] = (uint32_t)pk;

    if (blockIdx.x == 0 && threadIdx.x < 6) {   // pad output slots E..E+5
        int k = threadIdx.x;
        int stage = k >> 1, m = 131072 >> stage;
        int s, d;
        if ((k & 1) == 0) { s = m - 1; d = 0; } else { s = 0; d = m - 1; }
        int e = E_EDGES + k;
        out[SRC_OFF + e] = (float)s;
        out[DST_OFF + e] = (float)d;
        out[W_OFF + e]   = (stage == 2) ? 1.0f : 0.0f;
    }
}

// ---------------------------------------------------------------------------
// 1b) deg1: ONE-SHOT massive-TLP (r3-proven regime: 134M single-atomic
// threads hit 279 Gop/s). 4.2M threads, 1 coalesced load + 1 atomic each.
// ---------------------------------------------------------------------------
__global__ void __launch_bounds__(256) deg1_kernel(const int* __restrict__ ei,
        float* __restrict__ deg1) {
    unsigned idx = blockIdx.x * 256u + threadIdx.x;   // < E
    atomicAdd(&deg1[ei[E_EDGES + idx]], 1.0f);
}

// ---------------------------------------------------------------------------
// 2) tier_scan: 1 block x 1024 threads, hierarchical scan of 8192 wave counts
// -> per-wave bases {base3, base2partial}, totals {N3, N2}.
// ---------------------------------------------------------------------------
__global__ void __launch_bounds__(1024) tier_scan_kernel(const uint32_t* __restrict__ wc,
        uint2* __restrict__ wb, uint32_t* __restrict__ tot) {
    __shared__ uint32_t wt3[16], wt2[16];
    int t = threadIdx.x, lane = t & 63, w = t >> 6;   // 16 waves
    uint32_t v[8]; uint32_t s3 = 0, s2 = 0;
#pragma unroll
    for (int j = 0; j < 8; ++j) {
        v[j] = wc[t * 8 + j];
        s2 += v[j] & 0xFFFFu; s3 += v[j] >> 16;
    }
    uint32_t i3 = s3, i2 = s2;
    for (int off = 1; off < 64; off <<= 1) {
        uint32_t o3 = __shfl_up(i3, off);
        uint32_t o2 = __shfl_up(i2, off);
        if (lane >= off) { i3 += o3; i2 += o2; }
    }
    if (lane == 63) { wt3[w] = i3; wt2[w] = i2; }
    __syncthreads();
    uint32_t wb3 = 0, wb2 = 0;
#pragma unroll
    for (int k = 0; k < 16; ++k) {
        uint32_t m = (k < w) ? 1u : 0u;
        wb3 += m * wt3[k]; wb2 += m * wt2[k];
    }
    uint32_t r3 = wb3 + i3 - s3, r2 = wb2 + i2 - s2;   // exclusive global prefix
#pragma unroll
    for (int j = 0; j < 8; ++j) {
        wb[t * 8 + j] = make_uint2(r3, r2);
        r2 += v[j] & 0xFFFFu; r3 += v[j] >> 16;
    }
    if (t == 1023) { tot[0] = wb3 + i3; tot[1] = wb2 + i2; }
}

// ---------------------------------------------------------------------------
// 3) compact: thread-per-8-edges, ballot-prefix placement from per-wave bases
// + fused deg2/deg3 atomics (r13-proven). el = [t3 (el3 prefix) ; t2-only].
// ---------------------------------------------------------------------------
__global__ void __launch_bounds__(256) compact_kernel(const int* __restrict__ ei,
        const uint2* __restrict__ wb, const uint32_t* __restrict__ tot,
        int2* __restrict__ el, float* __restrict__ deg2, float* __restrict__ deg3) {
    int t = blockIdx.x * 256 + threadIdx.x;
    int lane = threadIdx.x & 63;
    int4 s0 = ((const int4*)ei)[2 * t];
    int4 s1 = ((const int4*)ei)[2 * t + 1];
    int4 d0 = ((const int4*)(ei + E_EDGES))[2 * t];
    int4 d1 = ((const int4*)(ei + E_EDGES))[2 * t + 1];
    uint2 base = wb[t >> 6];
    uint32_t r3 = base.x, r2 = tot[0] + base.y;
    uint64_t lt = (1ull << lane) - 1ull;
    int ss[8] = {s0.x, s0.y, s0.z, s0.w, s1.x, s1.y, s1.z, s1.w};
    int dd[8] = {d0.x, d0.y, d0.z, d0.w, d1.x, d1.y, d1.z, d1.w};
#pragma unroll
    for (int j = 0; j < 8; ++j) {
        int s = ss[j], d = dd[j];
        bool b3  = (s < 65536) & (d < 65536);
        bool b23 = (s < 131072) & (d < 131072);
        bool b2  = b23 & !b3;
        uint64_t m3 = __ballot(b3), m2 = __ballot(b2);
        if (b3) {
            el[r3 + (uint32_t)__popcll(m3 & lt)] = make_int2(s, d);
            atomicAdd(&deg3[d], 1.0f);
        }
        if (b2) {
            uint32_t p = r2 + (uint32_t)__popcll(m2 & lt);
            if (p < CAP2) el[p] = make_int2(s, d);
        }
        if (b23) atomicAdd(&deg2[d], 1.0f);
        r3 += (uint32_t)__popcll(m3); r2 += (uint32_t)__popcll(m2);
    }
}

// ---------------------------------------------------------------------------
// 4a) xform (stage 1): hs = dinv1*(x@W) bf16; agg init = hs (self-loop term).
// ---------------------------------------------------------------------------
__global__ void __launch_bounds__(256) xform1_kernel(const float* __restrict__ xin,
        const float* __restrict__ W, const float* __restrict__ deg1,
        bf16* __restrict__ hs, bf16* __restrict__ agg) {
    constexpr int FIN = 32, FOUT = 32, NPB = 8;
    __shared__ float sW[FIN * FOUT];
    __shared__ float sx[NPB * FIN];
    int tid = threadIdx.x;
    for (int i = tid; i < FIN * FOUT; i += 256) sW[i] = W[i];
    int node0 = blockIdx.x * NPB;
    for (int i = tid; i < NPB * FIN; i += 256) sx[i] = xin[node0 * FIN + i];
    __syncthreads();
    int nl = tid / FOUT, j = tid % FOUT;
    int node = node0 + nl;
    float acc = 0.0f;
#pragma unroll
    for (int k = 0; k < FIN; ++k) acc += sx[nl * FIN + k] * sW[k * FOUT + j];
    bf16 v = __float2bfloat16(rsqrtf(deg1[node] + 1.0f) * acc);
    hs[node * FOUT + j]  = v;
    agg[node * FOUT + j] = v;
}

// ---------------------------------------------------------------------------
// 4b) xform_pool (stages 2/3): pool previous agg inline during staging, then
// hs = dinv*(x@W); agg init = hs. dinv recomputed inline from deg.
// ---------------------------------------------------------------------------
template <int FOUT>
__global__ void __launch_bounds__(256) xform_pool_kernel(const bf16* __restrict__ aggp,
        const float* __restrict__ degp, int prevN, int prevPads, const float* __restrict__ biasp,
        const float* __restrict__ W, const float* __restrict__ deg, int curN,
        bf16* __restrict__ hs, bf16* __restrict__ agg) {
    constexpr int FIN = 32;
    constexpr int NPB = 256 / FOUT;
    __shared__ float sW[FIN * FOUT];
    __shared__ float sx[NPB * FIN];
    const unsigned short* ap = (const unsigned short*)aggp;
    int tid = threadIdx.x;
    for (int i = tid; i < FIN * FOUT; i += 256) sW[i] = W[i];
    int node0 = blockIdx.x * NPB;
    for (int i = tid; i < NPB * FIN; i += 256) {
        int nl = i / FIN, k = i % FIN;
        int g0 = 2 * (node0 + nl);
        float bb = biasp[k];
        float v0 = dinv_of(degp, g0,     prevN, prevPads) * b2f(ap[(size_t)g0 * FIN + k])       + bb;
        float v1 = dinv_of(degp, g0 + 1, prevN, prevPads) * b2f(ap[(size_t)(g0 + 1) * FIN + k]) + bb;
        sx[i] = fmaxf(fmaxf(v0, v1), 0.0f);
    }
    __syncthreads();
    int nl = tid / FOUT, j = tid % FOUT;
    int node = node0 + nl;
    float acc = 0.0f;
#pragma unroll
    for (int k = 0; k < FIN; ++k) acc += sx[nl * FIN + k] * sW[k * FOUT + j];
    bf16 v = __float2bfloat16(dinv_of(deg, node, curN, 1) * acc);
    hs[node * FOUT + j]  = v;
    agg[node * FOUT + j] = v;
}

// ---------------------------------------------------------------------------
// 5) scatters: flat, LOOP-FREE, pure fire-and-forget pk-bf16 atomics
// (r11/r13-proven: 212 us = 316 Gop/s atomic ceiling; NO mixed-in work).
// ---------------------------------------------------------------------------
__global__ void __launch_bounds__(256) scatter1_kernel(const int* __restrict__ ei,
        const bf16* __restrict__ hs, bf16* __restrict__ agg) {
    unsigned idx = blockIdx.x * 256u + threadIdx.x;
    int e = (int)(idx >> 4), p = (int)(idx & 15u);
    int s = ei[e], d = ei[E_EDGES + e];
    uint32_t hw = *(const uint32_t*)((const unsigned short*)hs + (size_t)s * 32 + 2 * p);
    pk_atomic_add_raw(agg + (size_t)d * 32 + 2 * p, hw);
}

template <int FOUT>
__global__ void __launch_bounds__(256) scatter_cmp_kernel(const int2* __restrict__ el,
        const uint32_t* __restrict__ tot, int useN3only,
        const bf16* __restrict__ hs, bf16* __restrict__ agg, int n) {
    constexpr int L = FOUT / 2;   // lanes per edge (16 / 8)
    unsigned idx = blockIdx.x * 256u + threadIdx.x;
    unsigned e = idx / L; int p = (int)(idx % L);
    uint32_t K = useN3only ? tot[0] : (tot[0] + tot[1]);
    if (e >= K + 2) return;
    int s, d;
    if (e < K)       { int2 sd = el[e]; s = sd.x; d = sd.y; }
    else if (e == K) { s = n - 1; d = 0; }
    else             { s = 0;     d = n - 1; }
    uint32_t hw = *(const uint32_t*)((const unsigned short*)hs + (size_t)s * FOUT + 2 * p);
    pk_atomic_add_raw(agg + (size_t)d * FOUT + 2 * p, hw);
}

// ---------------------------------------------------------------------------
// 6) final pool: out(f32) = relu(max over pair of dinv3*agg3 + b3)
// ---------------------------------------------------------------------------
__global__ void __launch_bounds__(256) pool_out_kernel(const bf16* __restrict__ agg,
        const float* __restrict__ deg3, const float* __restrict__ bias,
        float* __restrict__ outp) {
    unsigned idx = blockIdx.x * 256u + threadIdx.x;   // < 32768*16
    int i = (int)(idx >> 4), f = (int)(idx & 15);
    int g0 = 2 * i;
    float bb = bias[f];
    float v0 = dinv_of(deg3, g0,     65536, 1) * __bfloat162float(agg[(size_t)g0 * 16 + f])       + bb;
    float v1 = dinv_of(deg3, g0 + 1, 65536, 1) * __bfloat162float(agg[(size_t)(g0 + 1) * 16 + f]) + bb;
    outp[idx] = fmaxf(fmaxf(v0, v1), 0.0f);
}

// ---------------------------------------------------------------------------
// Workspace (<57 MiB):
//  @0M  agg bf16 (16/8/2 MB per stage)   @16M hs bf16 (16/8/2 MB)
//  @44M el int2 (8.2 MB, CAP2)
//  @55M deg1 (1M) @56M deg2 (.5M) @56.5M deg3 (.25M)
//  @59M wavecnt u32[8192]  @59M+256K wavebase uint2[8192]  @59M+768K totals
// ---------------------------------------------------------------------------
extern "C" void kernel_launch(void* const* d_in, const int* in_sizes, int n_in,
                              void* d_out, int out_size, void* d_ws, size_t ws_size,
                              hipStream_t stream) {
    const float* x  = (const float*)d_in[0];
    const int*   ei = (const int*)d_in[1];
    const float* W1 = (const float*)d_in[2];
    const float* b1 = (const float*)d_in[3];
    const float* W2 = (const float*)d_in[4];
    const float* b2 = (const float*)d_in[5];
    const float* W3 = (const float*)d_in[6];
    const float* b3 = (const float*)d_in[7];
    float* out = (float*)d_out;

    char* ws = (char*)d_ws;
    bf16*     agg   = (bf16*)ws;
    bf16*     hs    = (bf16*)(ws + (16u << 20));
    int2*     el    = (int2*)(ws + (44u << 20));
    float*    deg1  = (float*)(ws + (55u << 20));
    float*    deg2  = (float*)(ws + (56u << 20));
    float*    deg3  = (float*)(ws + (56u << 20) + (512u << 10));
    uint32_t* wcnt  = (uint32_t*)(ws + (59u << 20));
    uint2*    wbase = (uint2*)(ws + (59u << 20) + (256u << 10));
    uint32_t* totb  = (uint32_t*)(ws + (59u << 20) + (768u << 10));

    // prep: zero degs; pure-streaming outputs+counts; one-shot deg1;
    // scan; compact(+deg2/3)
    hipMemsetAsync(deg1, 0, (1u << 20) + (768u << 10), stream);
    out_count_kernel<<<2048, 256, 0, stream>>>(ei, out, wcnt);
    deg1_kernel<<<E_EDGES / 256, 256, 0, stream>>>(ei, deg1);
    tier_scan_kernel<<<1, 1024, 0, stream>>>(wcnt, wbase, totb);
    compact_kernel<<<2048, 256, 0, stream>>>(ei, wbase, totb, el, deg2, deg3);

    // stage 1: n=262144, 32->32 (all edges; ei directly)
    xform1_kernel<<<N_NODES / 8, 256, 0, stream>>>(x, W1, deg1, hs, agg);
    scatter1_kernel<<<E_EDGES * 16 / 256, 256, 0, stream>>>(ei, hs, agg);

    // stage 2: n=131072, 32->32 (pool fused into xform; el full list + pads)
    xform_pool_kernel<32><<<131072 / 8, 256, 0, stream>>>(agg, deg1, 262144, 0, b1,
                                                          W2, deg2, 131072, hs, agg);
    scatter_cmp_kernel<32><<<(int)(((unsigned)(CAP2 + 2) * 16 + 255) / 256), 256, 0, stream>>>(
        el, totb, 0, hs, agg, 131072);

    // stage 3: n=65536, 32->16 (pool fused; el3 prefix + pads)
    xform_pool_kernel<16><<<65536 / 16, 256, 0, stream>>>(agg, deg2, 131072, 1, b2,
                                                          W3, deg3, 65536, hs, agg);
    scatter_cmp_kernel<16><<<(int)(((unsigned)(CAP3 + 2) * 8 + 255) / 256), 256, 0, stream>>>(
        el, totb, 1, hs, agg, 65536);

    // final pool -> f32 out
    pool_out_kernel<<<32768 * 16 / 256, 256, 0, stream>>>(agg, deg3, b3, out);
}

// Round 17
// 645.023 us; speedup vs baseline: 1.1548x; 1.0271x over previous
//
#include <hip/hip_runtime.h>
#include <hip/hip_bf16.h>
#include <stdint.h>

#define N_NODES 262144
#define E_EDGES 4194304
#define EPAD    4194310            // E + 6
#define SRC_OFF 524288
#define DST_OFF (524288 + 4194310)
#define W_OFF   (524288 + 2 * 4194310)
#define CAP2    1064960            // el capacity (t3+t2 expected 1.0486M, +17 sigma)
#define CAP3    270336             // scatter3 edge cap (expected 262144, +16 sigma)

using bf16 = __hip_bfloat16;
typedef float f4v __attribute__((ext_vector_type(4)));
typedef float f2v __attribute__((ext_vector_type(2)));

__device__ __forceinline__ float b2f(unsigned int u) {
    union { unsigned int i; float f; } v; v.i = u << 16; return v.f;
}

// raw packed 2xbf16 atomic add (fire-and-forget; hs pre-scaled by dinv[s])
__device__ __forceinline__ void pk_atomic_add_raw(bf16* addr, uint32_t data) {
    asm volatile("global_atomic_pk_add_bf16 %0, %1, off" :: "v"(addr), "v"(data) : "memory");
}

// inline symmetric-norm factor: dinv(i) = rsqrt(deg[i] + 1 [+1 if pad endpoint])
__device__ __forceinline__ float dinv_of(const float* __restrict__ deg, int i, int n, int pads) {
    float extra = (pads && (i == 0 || i == n - 1)) ? 1.0f : 0.0f;
    return rsqrtf(deg[i] + 1.0f + extra);
}

// ---------------------------------------------------------------------------
// 1) tier_hist: thread-per-8-edges, LOOP-FREE. Edge outputs (NT stores) +
// fused deg1 atomics + per-wave tier counts (wave covers 512 edges).
// wc[wave] = c2 | (c3<<16); c3 = both<65536, c2 = both<131072 && !c3.
// ---------------------------------------------------------------------------
__global__ void __launch_bounds__(256) tier_hist_kernel(const int* __restrict__ ei,
        float* __restrict__ out, uint32_t* __restrict__ wc, float* __restrict__ deg1) {
    int t = blockIdx.x * 256 + threadIdx.x;          // t < E/8 = 524288
    int4 s0 = ((const int4*)ei)[2 * t];
    int4 s1 = ((const int4*)ei)[2 * t + 1];
    int4 d0 = ((const int4*)(ei + E_EDGES))[2 * t];
    int4 d1 = ((const int4*)(ei + E_EDGES))[2 * t + 1];

    f4v v;
    v = (f4v){(float)s0.x, (float)s0.y, (float)s0.z, (float)s0.w};
    __builtin_nontemporal_store(v, (f4v*)(out + SRC_OFF) + 2 * t);
    v = (f4v){(float)s1.x, (float)s1.y, (float)s1.z, (float)s1.w};
    __builtin_nontemporal_store(v, (f4v*)(out + SRC_OFF) + 2 * t + 1);
    f2v w2;
    w2 = (f2v){(float)d0.x, (float)d0.y}; __builtin_nontemporal_store(w2, (f2v*)(out + DST_OFF) + 4 * t);
    w2 = (f2v){(float)d0.z, (float)d0.w}; __builtin_nontemporal_store(w2, (f2v*)(out + DST_OFF) + 4 * t + 1);
    w2 = (f2v){(float)d1.x, (float)d1.y}; __builtin_nontemporal_store(w2, (f2v*)(out + DST_OFF) + 4 * t + 2);
    w2 = (f2v){(float)d1.z, (float)d1.w}; __builtin_nontemporal_store(w2, (f2v*)(out + DST_OFF) + 4 * t + 3);
    v = (f4v){(s0.x < 32768 && d0.x < 32768) ? 1.0f : 0.0f,
              (s0.y < 32768 && d0.y < 32768) ? 1.0f : 0.0f,
              (s0.z < 32768 && d0.z < 32768) ? 1.0f : 0.0f,
              (s0.w < 32768 && d0.w < 32768) ? 1.0f : 0.0f};
    __builtin_nontemporal_store(v, (f4v*)(out + W_OFF) + 2 * t);
    v = (f4v){(s1.x < 32768 && d1.x < 32768) ? 1.0f : 0.0f,
              (s1.y < 32768 && d1.y < 32768) ? 1.0f : 0.0f,
              (s1.z < 32768 && d1.z < 32768) ? 1.0f : 0.0f,
              (s1.w < 32768 && d1.w < 32768) ? 1.0f : 0.0f};
    __builtin_nontemporal_store(v, (f4v*)(out + W_OFF) + 2 * t + 1);

    atomicAdd(&deg1[d0.x], 1.0f); atomicAdd(&deg1[d0.y], 1.0f);
    atomicAdd(&deg1[d0.z], 1.0f); atomicAdd(&deg1[d0.w], 1.0f);
    atomicAdd(&deg1[d1.x], 1.0f); atomicAdd(&deg1[d1.y], 1.0f);
    atomicAdd(&deg1[d1.z], 1.0f); atomicAdd(&deg1[d1.w], 1.0f);

    int c3 = 0, c2 = 0;
    int ss[8] = {s0.x, s0.y, s0.z, s0.w, s1.x, s1.y, s1.z, s1.w};
    int dd[8] = {d0.x, d0.y, d0.z, d0.w, d1.x, d1.y, d1.z, d1.w};
#pragma unroll
    for (int j = 0; j < 8; ++j) {
        bool b3  = (ss[j] < 65536) & (dd[j] < 65536);
        bool b23 = (ss[j] < 131072) & (dd[j] < 131072);
        c3 += b3; c2 += (b23 & !b3);
    }
    int pk = c2 | (c3 << 16);   // fields <= 512, no overflow
    pk += __shfl_xor(pk, 32); pk += __shfl_xor(pk, 16); pk += __shfl_xor(pk, 8);
    pk += __shfl_xor(pk, 4);  pk += __shfl_xor(pk, 2);  pk += __shfl_xor(pk, 1);
    if ((threadIdx.x & 63) == 0) wc[t >> 6] = (uint32_t)pk;
}

// ---------------------------------------------------------------------------
// 2) tier_scan: 1 block x 1024 threads, hierarchical scan of 8192 wave counts
// -> per-wave bases {base3, base2partial}, totals {N3, N2}, pad slots E..E+5.
// ---------------------------------------------------------------------------
__global__ void __launch_bounds__(1024) tier_scan_kernel(const uint32_t* __restrict__ wc,
        uint2* __restrict__ wb, uint32_t* __restrict__ tot, float* __restrict__ out) {
    __shared__ uint32_t wt3[16], wt2[16];
    int t = threadIdx.x, lane = t & 63, w = t >> 6;   // 16 waves
    uint32_t v[8]; uint32_t s3 = 0, s2 = 0;
#pragma unroll
    for (int j = 0; j < 8; ++j) {
        v[j] = wc[t * 8 + j];
        s2 += v[j] & 0xFFFFu; s3 += v[j] >> 16;
    }
    // wave-level inclusive scan (width 64)
    uint32_t i3 = s3, i2 = s2;
    for (int off = 1; off < 64; off <<= 1) {
        uint32_t o3 = __shfl_up(i3, off);
        uint32_t o2 = __shfl_up(i2, off);
        if (lane >= off) { i3 += o3; i2 += o2; }
    }
    if (lane == 63) { wt3[w] = i3; wt2[w] = i2; }
    __syncthreads();
    uint32_t wb3 = 0, wb2 = 0;
#pragma unroll
    for (int k = 0; k < 16; ++k) {
        uint32_t m = (k < w) ? 1u : 0u;
        wb3 += m * wt3[k]; wb2 += m * wt2[k];
    }
    uint32_t r3 = wb3 + i3 - s3, r2 = wb2 + i2 - s2;   // exclusive global prefix
#pragma unroll
    for (int j = 0; j < 8; ++j) {
        wb[t * 8 + j] = make_uint2(r3, r2);
        r2 += v[j] & 0xFFFFu; r3 += v[j] >> 16;
    }
    if (t == 1023) { tot[0] = wb3 + i3; tot[1] = wb2 + i2; }
    if (t < 6) {
        int stage = t >> 1, m = 131072 >> stage;
        int s, d;
        if ((t & 1) == 0) { s = m - 1; d = 0; } else { s = 0; d = m - 1; }
        int e = E_EDGES + t;
        out[SRC_OFF + e] = (float)s;
        out[DST_OFF + e] = (float)d;
        out[W_OFF + e]   = (stage == 2) ? 1.0f : 0.0f;
    }
}

// ---------------------------------------------------------------------------
// 3) compact: thread-per-8-edges, ballot-prefix placement from per-wave bases
// + fused deg2/deg3 atomics. el = [t3 edges (el3 prefix) ; t2-only edges].
// ---------------------------------------------------------------------------
__global__ void __launch_bounds__(256) compact_kernel(const int* __restrict__ ei,
        const uint2* __restrict__ wb, const uint32_t* __restrict__ tot,
        int2* __restrict__ el, float* __restrict__ deg2, float* __restrict__ deg3) {
    int t = blockIdx.x * 256 + threadIdx.x;
    int lane = threadIdx.x & 63;
    int4 s0 = ((const int4*)ei)[2 * t];
    int4 s1 = ((const int4*)ei)[2 * t + 1];
    int4 d0 = ((const int4*)(ei + E_EDGES))[2 * t];
    int4 d1 = ((const int4*)(ei + E_EDGES))[2 * t + 1];
    uint2 base = wb[t >> 6];
    uint32_t r3 = base.x, r2 = tot[0] + base.y;
    uint64_t lt = (1ull << lane) - 1ull;
    int ss[8] = {s0.x, s0.y, s0.z, s0.w, s1.x, s1.y, s1.z, s1.w};
    int dd[8] = {d0.x, d0.y, d0.z, d0.w, d1.x, d1.y, d1.z, d1.w};
#pragma unroll
    for (int j = 0; j < 8; ++j) {
        int s = ss[j], d = dd[j];
        bool b3  = (s < 65536) & (d < 65536);
        bool b23 = (s < 131072) & (d < 131072);
        bool b2  = b23 & !b3;
        uint64_t m3 = __ballot(b3), m2 = __ballot(b2);
        if (b3) {
            el[r3 + (uint32_t)__popcll(m3 & lt)] = make_int2(s, d);
            atomicAdd(&deg3[d], 1.0f);
        }
        if (b2) {
            uint32_t p = r2 + (uint32_t)__popcll(m2 & lt);
            if (p < CAP2) el[p] = make_int2(s, d);
        }
        if (b23) atomicAdd(&deg2[d], 1.0f);
        r3 += (uint32_t)__popcll(m3); r2 += (uint32_t)__popcll(m2);
    }
}

// ---------------------------------------------------------------------------
// 4a) xform (stage 1): hs = dinv1*(x@W) bf16; agg init = hs (self-loop term).
// ---------------------------------------------------------------------------
__global__ void __launch_bounds__(256) xform1_kernel(const float* __restrict__ xin,
        const float* __restrict__ W, const float* __restrict__ deg1,
        bf16* __restrict__ hs, bf16* __restrict__ agg) {
    constexpr int FIN = 32, FOUT = 32, NPB = 8;
    __shared__ float sW[FIN * FOUT];
    __shared__ float sx[NPB * FIN];
    int tid = threadIdx.x;
    for (int i = tid; i < FIN * FOUT; i += 256) sW[i] = W[i];
    int node0 = blockIdx.x * NPB;
    for (int i = tid; i < NPB * FIN; i += 256) sx[i] = xin[node0 * FIN + i];
    __syncthreads();
    int nl = tid / FOUT, j = tid % FOUT;
    int node = node0 + nl;
    float acc = 0.0f;
#pragma unroll
    for (int k = 0; k < FIN; ++k) acc += sx[nl * FIN + k] * sW[k * FOUT + j];
    bf16 v = __float2bfloat16(rsqrtf(deg1[node] + 1.0f) * acc);
    hs[node * FOUT + j]  = v;
    agg[node * FOUT + j] = v;
}

// ---------------------------------------------------------------------------
// 4b) xform_pool (stages 2/3): pool previous agg inline during staging, then
// hs = dinv*(x@W); agg init = hs. dinv factors recomputed inline from deg.
// ---------------------------------------------------------------------------
template <int FOUT>
__global__ void __launch_bounds__(256) xform_pool_kernel(const bf16* __restrict__ aggp,
        const float* __restrict__ degp, int prevN, int prevPads, const float* __restrict__ biasp,
        const float* __restrict__ W, const float* __restrict__ deg, int curN,
        bf16* __restrict__ hs, bf16* __restrict__ agg) {
    constexpr int FIN = 32;
    constexpr int NPB = 256 / FOUT;
    __shared__ float sW[FIN * FOUT];
    __shared__ float sx[NPB * FIN];
    const unsigned short* ap = (const unsigned short*)aggp;
    int tid = threadIdx.x;
    for (int i = tid; i < FIN * FOUT; i += 256) sW[i] = W[i];
    int node0 = blockIdx.x * NPB;
    for (int i = tid; i < NPB * FIN; i += 256) {
        int nl = i / FIN, k = i % FIN;
        int g0 = 2 * (node0 + nl);
        float bb = biasp[k];
        float v0 = dinv_of(degp, g0,     prevN, prevPads) * b2f(ap[(size_t)g0 * FIN + k])       + bb;
        float v1 = dinv_of(degp, g0 + 1, prevN, prevPads) * b2f(ap[(size_t)(g0 + 1) * FIN + k]) + bb;
        sx[i] = fmaxf(fmaxf(v0, v1), 0.0f);
    }
    __syncthreads();
    int nl = tid / FOUT, j = tid % FOUT;
    int node = node0 + nl;
    float acc = 0.0f;
#pragma unroll
    for (int k = 0; k < FIN; ++k) acc += sx[nl * FIN + k] * sW[k * FOUT + j];
    bf16 v = __float2bfloat16(dinv_of(deg, node, curN, 1) * acc);
    hs[node * FOUT + j]  = v;
    agg[node * FOUT + j] = v;
}

// ---------------------------------------------------------------------------
// 5) scatters: flat, LOOP-FREE, fire-and-forget pk-bf16 atomics (212 us =
// 316 Gop/s device atomic ceiling, invariant across r11-r16).
// ---------------------------------------------------------------------------
__global__ void __launch_bounds__(256) scatter1_kernel(const int* __restrict__ ei,
        const bf16* __restrict__ hs, bf16* __restrict__ agg) {
    unsigned idx = blockIdx.x * 256u + threadIdx.x;
    int e = (int)(idx >> 4), p = (int)(idx & 15u);
    int s = ei[e], d = ei[E_EDGES + e];
    uint32_t hw = *(const uint32_t*)((const unsigned short*)hs + (size_t)s * 32 + 2 * p);
    pk_atomic_add_raw(agg + (size_t)d * 32 + 2 * p, hw);
}

template <int FOUT>
__global__ void __launch_bounds__(256) scatter_cmp_kernel(const int2* __restrict__ el,
        const uint32_t* __restrict__ tot, int useN3only,
        const bf16* __restrict__ hs, bf16* __restrict__ agg, int n) {
    constexpr int L = FOUT / 2;   // lanes per edge (16 / 8)
    unsigned idx = blockIdx.x * 256u + threadIdx.x;
    unsigned e = idx / L; int p = (int)(idx % L);
    uint32_t K = useN3only ? tot[0] : (tot[0] + tot[1]);
    if (e >= K + 2) return;
    int s, d;
    if (e < K)       { int2 sd = el[e]; s = sd.x; d = sd.y; }
    else if (e == K) { s = n - 1; d = 0; }
    else             { s = 0;     d = n - 1; }
    uint32_t hw = *(const uint32_t*)((const unsigned short*)hs + (size_t)s * FOUT + 2 * p);
    pk_atomic_add_raw(agg + (size_t)d * FOUT + 2 * p, hw);
}

// ---------------------------------------------------------------------------
// 6) final pool: out(f32) = relu(max over pair of dinv3*agg3 + b3)
// ---------------------------------------------------------------------------
__global__ void __launch_bounds__(256) pool_out_kernel(const bf16* __restrict__ agg,
        const float* __restrict__ deg3, const float* __restrict__ bias,
        float* __restrict__ outp) {
    unsigned idx = blockIdx.x * 256u + threadIdx.x;   // < 32768*16
    int i = (int)(idx >> 4), f = (int)(idx & 15);
    int g0 = 2 * i;
    float bb = bias[f];
    float v0 = dinv_of(deg3, g0,     65536, 1) * __bfloat162float(agg[(size_t)g0 * 16 + f])       + bb;
    float v1 = dinv_of(deg3, g0 + 1, 65536, 1) * __bfloat162float(agg[(size_t)(g0 + 1) * 16 + f]) + bb;
    outp[idx] = fmaxf(fmaxf(v0, v1), 0.0f);
}

// ---------------------------------------------------------------------------
// Workspace (<60 MiB):
//  @0M  agg bf16 (16/8/2 MB per stage)   @16M hs bf16 (16/8/2 MB)
//  @44M el int2 (8.2 MB, CAP2)
//  @55M deg1 (1M) @56M deg2 (.5M) @56.5M deg3 (.25M)
//  @59M wavecnt u32[8192]  @59M+256K wavebase uint2[8192]  @59M+768K totals
// ---------------------------------------------------------------------------
extern "C" void kernel_launch(void* const* d_in, const int* in_sizes, int n_in,
                              void* d_out, int out_size, void* d_ws, size_t ws_size,
                              hipStream_t stream) {
    const float* x  = (const float*)d_in[0];
    const int*   ei = (const int*)d_in[1];
    const float* W1 = (const float*)d_in[2];
    const float* b1 = (const float*)d_in[3];
    const float* W2 = (const float*)d_in[4];
    const float* b2 = (const float*)d_in[5];
    const float* W3 = (const float*)d_in[6];
    const float* b3 = (const float*)d_in[7];
    float* out = (float*)d_out;

    char* ws = (char*)d_ws;
    bf16*     agg   = (bf16*)ws;
    bf16*     hs    = (bf16*)(ws + (16u << 20));
    int2*     el    = (int2*)(ws + (44u << 20));
    float*    deg1  = (float*)(ws + (55u << 20));
    float*    deg2  = (float*)(ws + (56u << 20));
    float*    deg3  = (float*)(ws + (56u << 20) + (512u << 10));
    uint32_t* wcnt  = (uint32_t*)(ws + (59u << 20));
    uint2*    wbase = (uint2*)(ws + (59u << 20) + (256u << 10));
    uint32_t* totb  = (uint32_t*)(ws + (59u << 20) + (768u << 10));

    // prep: zero degs, fused hist(+deg1) -> fast scan -> compact(+deg2/3)
    hipMemsetAsync(deg1, 0, (1u << 20) + (768u << 10), stream);
    tier_hist_kernel<<<2048, 256, 0, stream>>>(ei, out, wcnt, deg1);
    tier_scan_kernel<<<1, 1024, 0, stream>>>(wcnt, wbase, totb, out);
    compact_kernel<<<2048, 256, 0, stream>>>(ei, wbase, totb, el, deg2, deg3);

    // stage 1: n=262144, 32->32 (all edges; ei directly)
    xform1_kernel<<<N_NODES / 8, 256, 0, stream>>>(x, W1, deg1, hs, agg);
    scatter1_kernel<<<E_EDGES * 16 / 256, 256, 0, stream>>>(ei, hs, agg);

    // stage 2: n=131072, 32->32 (pool fused into xform; el full list + pads)
    xform_pool_kernel<32><<<131072 / 8, 256, 0, stream>>>(agg, deg1, 262144, 0, b1,
                                                          W2, deg2, 131072, hs, agg);
    scatter_cmp_kernel<32><<<(int)(((unsigned)(CAP2 + 2) * 16 + 255) / 256), 256, 0, stream>>>(
        el, totb, 0, hs, agg, 131072);

    // stage 3: n=65536, 32->16 (pool fused; el3 prefix + pads)
    xform_pool_kernel<16><<<65536 / 16, 256, 0, stream>>>(agg, deg2, 131072, 1, b2,
                                                          W3, deg3, 65536, hs, agg);
    scatter_cmp_kernel<16><<<(int)(((unsigned)(CAP3 + 2) * 8 + 255) / 256), 256, 0, stream>>>(
        el, totb, 1, hs, agg, 65536);

    // final pool -> f32 out
    pool_out_kernel<<<32768 * 16 / 256, 256, 0, stream>>>(agg, deg3, b3, out);
}